// Round 14
// baseline (429.913 us; speedup 1.0000x reference)
//
#include <hip/hip_runtime.h>
#include <cstdint>
#include <cstddef>

typedef _Float16 f16;
typedef __attribute__((ext_vector_type(4))) _Float16 half4;
typedef __attribute__((ext_vector_type(8))) _Float16 half8;
typedef __attribute__((ext_vector_type(4))) float f32x4;

constexpr int Bb = 2, Ee = 1024, Dd = 1024, Hh = 2048, NHh = 16, HDd = 128, Ss = 2048;
constexpr float SCALE = 0.08838834764831845f;  // HD^-0.5
constexpr int PSTR = 84;                       // Plds row stride (f16) — bank-spread

#define DEVINL __device__ __forceinline__
#define GLD_LDS(gp, lp) \
  __builtin_amdgcn_global_load_lds((const __attribute__((address_space(1))) void*)(gp), \
                                   (__attribute__((address_space(3))) void*)(lp), 16, 0, 0)

DEVINL f16 f2h(float x) { return (f16)x; }
DEVINL float h2f(f16 x) { return (float)x; }

// ---------------- conversions ----------------
__global__ void convert_hs_k(const float* __restrict__ hid, const float* __restrict__ enc,
                             f16* __restrict__ dst) {
  size_t idx = ((size_t)blockIdx.x * 256 + threadIdx.x) * 8;  // over B*S*H = 2^23
  int b = (int)(idx >> 22);
  size_t r = idx & ((1ull << 22) - 1);
  int s = (int)(r >> 11);
  int hc = (int)(r & 2047);
  const float* src = (s < Ee) ? (enc + (((size_t)b * Ee + s) << 11) + hc)
                              : (hid + (((size_t)b * Dd + (s - Ee)) << 11) + hc);
  float4 x0 = *(const float4*)src;
  float4 x1 = *(const float4*)(src + 4);
  union { f16 u[8]; uint4 v; } o;
  o.u[0] = f2h(x0.x); o.u[1] = f2h(x0.y); o.u[2] = f2h(x0.z); o.u[3] = f2h(x0.w);
  o.u[4] = f2h(x1.x); o.u[5] = f2h(x1.y); o.u[6] = f2h(x1.z); o.u[7] = f2h(x1.w);
  *(uint4*)(dst + idx) = o.v;
}

__global__ void convert_w_k(const float* __restrict__ w0, const float* __restrict__ w1,
                            const float* __restrict__ w2, const float* __restrict__ w3,
                            f16* __restrict__ dst) {
  const float* srcs[4] = {w0, w1, w2, w3};
  int z = blockIdx.y;
  size_t idx = ((size_t)blockIdx.x * 256 + threadIdx.x) * 8;  // over H*H = 2^22
  const float* s = srcs[z] + idx;
  f16* d = dst + (size_t)z * Hh * Hh + idx;
  float4 x0 = *(const float4*)s;
  float4 x1 = *(const float4*)(s + 4);
  union { f16 u[8]; uint4 v; } o;
  o.u[0] = f2h(x0.x); o.u[1] = f2h(x0.y); o.u[2] = f2h(x0.z); o.u[3] = f2h(x0.w);
  o.u[4] = f2h(x1.x); o.u[5] = f2h(x1.y); o.u[6] = f2h(x1.z); o.u[7] = f2h(x1.w);
  *(uint4*)d = o.v;
}

// ---------------- GEMM: C[M x 2048] = A[M x 2048] * Bw[2048 x 2048]^T ----------------
// (r13 epilogue-vectorized version — neutral vs r10, kept for fewer stores)
template <int MODE>
__global__ __launch_bounds__(256) void gemm_k(const f16* __restrict__ A,
                                              const f16* __restrict__ Bw,
                                              void* __restrict__ Cout) {
  __shared__ f16 Alds[128 * 64];
  __shared__ f16 Blds[128 * 64];
  const int tid = threadIdx.x;
  const int lane = tid & 63, w = tid >> 6;
  const int lr = lane & 15, lq = lane >> 4;
  const int m0 = blockIdx.y * 128, n0 = blockIdx.x * 128;
  const int wm = (w >> 1) * 64, wn = (w & 1) * 64;
  f32x4 acc[4][4] = {};

  for (int k0 = 0; k0 < 2048; k0 += 64) {
    __syncthreads();
#pragma unroll
    for (int t = 0; t < 4; ++t) {
      int c = t * 256 + tid;
      int row = c >> 3, cof = (c & 7) << 3;
      const f16* ga = A + ((size_t)(m0 + row) << 11) + k0 + cof;
      const f16* gb = Bw + ((size_t)(n0 + row) << 11) + k0 + cof;
      int lo = (t * 256 + w * 64) * 8;
      GLD_LDS(ga, Alds + lo);
      GLD_LDS(gb, Blds + lo);
    }
    __syncthreads();
#pragma unroll
    for (int kk = 0; kk < 2; ++kk) {
      half8 af[4], bf[4];
#pragma unroll
      for (int i = 0; i < 4; ++i) {
        af[i] = *(const half8*)(Alds + (wm + i * 16 + lr) * 64 + kk * 32 + lq * 8);
        bf[i] = *(const half8*)(Blds + (wn + i * 16 + lr) * 64 + kk * 32 + lq * 8);
      }
#pragma unroll
      for (int i = 0; i < 4; ++i)
#pragma unroll
        for (int j = 0; j < 4; ++j) {
          if constexpr (MODE == 1)
            acc[i][j] = __builtin_amdgcn_mfma_f32_16x16x32_f16(af[i], bf[j], acc[i][j], 0, 0, 0);
          else  // SWAPPED: lane = one m-row, 4 consecutive n-cols
            acc[i][j] = __builtin_amdgcn_mfma_f32_16x16x32_f16(bf[j], af[i], acc[i][j], 0, 0, 0);
        }
    }
  }

#pragma unroll
  for (int i = 0; i < 4; ++i) {
#pragma unroll
    for (int j = 0; j < 4; ++j) {
      if constexpr (MODE == 1) {
        const int col = n0 + wn + j * 16 + lr;
        const int hh = col >> 7, hd = col & 127;
        const int row0 = m0 + wm + i * 16 + lq * 4;
        const int bb = row0 >> 11, s0 = row0 & 2047;
        half4 v = {f2h(acc[i][j][0]), f2h(acc[i][j][1]), f2h(acc[i][j][2]), f2h(acc[i][j][3])};
        *(half4*)((f16*)Cout + ((((size_t)bb * NHh + hh) * HDd + hd) << 11) + s0) = v;
      } else if constexpr (MODE == 0) {
        const int row = m0 + wm + i * 16 + lr;
        const int bb = row >> 11, s = row & 2047;
        const int col0 = n0 + wn + j * 16 + lq * 4;
        const int hh = col0 >> 7, hd0 = col0 & 127;
        half4 v = {f2h(acc[i][j][0]), f2h(acc[i][j][1]), f2h(acc[i][j][2]), f2h(acc[i][j][3])};
        *(half4*)((f16*)Cout + ((((size_t)bb * NHh + hh) * Ss + s) << 7) + hd0) = v;
      } else {
        const int row = m0 + wm + i * 16 + lr;
        const int col0 = n0 + wn + j * 16 + lq * 4;
        *(f32x4*)((float*)Cout + ((size_t)row << 11) + col0) = acc[i][j];
      }
    }
  }
}

// ---------------- RoPE on decoder rows of q,k ----------------
__global__ void rope_k(f16* __restrict__ q, f16* __restrict__ k,
                       const float* __restrict__ cosp, const float* __restrict__ sinp) {
  size_t idx = (size_t)blockIdx.x * 256 + threadIdx.x;  // B*NH*D*64 = 2^21
  const int d = (int)(idx & 63);
  const int sdec = (int)((idx >> 6) & 1023);
  const int h = (int)((idx >> 16) & 15);
  const int b = (int)(idx >> 20);
  const size_t base = (((size_t)b * NHh + h) * Ss + Ee + sdec) * HDd;
  const size_t cbase = ((size_t)b * Dd + sdec) * HDd;
  const float c1 = cosp[cbase + d], s1 = sinp[cbase + d];
  const float c2 = cosp[cbase + d + 64], s2 = sinp[cbase + d + 64];
  {
    float x1 = h2f(q[base + d]), x2 = h2f(q[base + d + 64]);
    q[base + d] = f2h(x1 * c1 - x2 * s1);
    q[base + d + 64] = f2h(x2 * c2 + x1 * s2);
  }
  {
    float x1 = h2f(k[base + d]), x2 = h2f(k[base + d + 64]);
    k[base + d] = f2h(x1 * c1 - x2 * s1);
    k[base + d + 64] = f2h(x2 * c2 + x1 * s2);
  }
}

// ---------------- fused attention ----------------
// r13 base + ONE change: pass 2's __syncthreads() replaced with a hand-rolled
// counted-vmcnt barrier (T4, m218). __syncthreads emits s_waitcnt vmcnt(0)
// which drains this tile's 4 nt stores to HBM (~900cy) every tile. vmcnt(4)
// waits only for the 4 staging global_load_lds (issued FIRST, pinned by
// sched_barrier) and leaves the 4 nt stores in flight across the next tile's
// compute. In-order vmcnt retirement makes the count exact.
__global__ __launch_bounds__(256) void attn_k(const f16* __restrict__ qw,
                                              const f16* __restrict__ kw,
                                              const f16* __restrict__ vw,
                                              float* __restrict__ attn,
                                              f16* __restrict__ ctx) {
  __shared__ f16 Kb[2][8192];
  __shared__ f16 Vb[2][8192];
  __shared__ f16 Plds[4][16 * PSTR];
  const int tid = threadIdx.x;
  const int lane = tid & 63, w = tid >> 6;
  const int lr = lane & 15, lq = lane >> 4;

  // XCD-aware remap: 8 chunks of 128 blocks; heavy-first q-tile order.
  const int n = blockIdx.x;
  const int orig = (n & 7) * 128 + (n >> 3);
  const int qt = orig & 31;
  const int h = (orig >> 5) & 15;
  const int b = orig >> 9;
  const int q0 = (31 - qt) * 64;
  const bool dec = q0 >= Ee;
  const int kt_lim = dec ? (q0 / 64 + 1) : (Ee / 64);
  const size_t bh = (size_t)b * NHh + h;

#define STAGE_K(dst, kt_)                                                        \
  {                                                                              \
    _Pragma("unroll") for (int t = 0; t < 4; ++t) {                              \
      int c = t * 256 + tid;                                                     \
      int row = c >> 4;                                                          \
      int gs = (c & 15) ^ (row & 7);                                             \
      GLD_LDS(kw + (bh * Ss + (kt_) * 64 + row) * HDd + gs * 8, (dst) + c * 8);  \
    }                                                                            \
  }
#define STAGE_V(dst, kt_)                                                        \
  {                                                                              \
    _Pragma("unroll") for (int t = 0; t < 4; ++t) {                              \
      int c = t * 256 + tid;                                                     \
      int row = c >> 3;                                                          \
      int gs = (c & 7) ^ (row & 7);                                              \
      GLD_LDS(vw + (bh * HDd + row) * Ss + (kt_) * 64 + gs * 8, (dst) + c * 8);  \
    }                                                                            \
  }

  // Q fragments: wave's 16 rows x 128 dims, kept in registers
  const f16* qbase = qw + (bh * Ss + q0 + w * 16 + lr) * HDd + lq * 8;
  half8 aq[4];
#pragma unroll
  for (int kk = 0; kk < 4; ++kk) aq[kk] = *(const half8*)(qbase + kk * 32);

  const int qrow = q0 + w * 16 + lr;  // this lane's q-row (swapped layout)
  float lsum1 = 0.f;
  f32x4 accv[8] = {};

  // ---- pass 1: row sums + UNNORMALIZED PV (one barrier per tile) ----
  STAGE_K(Kb[0], 0);
  if (dec) STAGE_V(Vb[0], 0);
  __syncthreads();
  int cur = 0;
  for (int kt = 0; kt < kt_lim; ++kt) {
    if (kt + 1 < kt_lim) {
      STAGE_K(Kb[cur ^ 1], kt + 1);            // overlaps compute below
      if (dec) STAGE_V(Vb[cur ^ 1], kt + 1);
    }
    const f16* Kp = Kb[cur];
#pragma unroll
    for (int j = 0; j < 4; ++j) {
      f32x4 sc = {0.f, 0.f, 0.f, 0.f};
#pragma unroll
      for (int kk = 0; kk < 4; ++kk) {
        half8 bk = *(const half8*)(Kp + (j * 16 + lr) * 128 + (((kk << 2) + lq) ^ (lr & 7)) * 8);
        sc = __builtin_amdgcn_mfma_f32_16x16x32_f16(bk, aq[kk], sc, 0, 0, 0);  // SWAPPED
      }
      const int c0 = kt * 64 + j * 16 + lq * 4;
      union { f16 u[4]; uint2 v2; } pw;
#pragma unroll
      for (int jj = 0; jj < 4; ++jj) {
        const int col = c0 + jj;
        bool masked = dec && col >= Ee && col > qrow;
        float pu = masked ? 0.f : __expf(sc[jj] * SCALE);  // unnormalized, <= e^~6
        lsum1 += pu;
        pw.u[jj] = f2h(pu);
      }
      if (dec) *(uint2*)(&Plds[w][lr * PSTR + j * 16 + lq * 4]) = pw.v2;
    }
    if (dec) {
      // Plds[w] wave-private: same-wave lgkmcnt ordering suffices, no barrier.
#pragma unroll
      for (int kk2 = 0; kk2 < 2; ++kk2) {
        half8 ap = *(const half8*)(&Plds[w][lr * PSTR + kk2 * 32 + lq * 8]);
#pragma unroll
        for (int nt = 0; nt < 8; ++nt) {
          half8 bv = *(const half8*)(Vb[cur] + (nt * 16 + lr) * 64 + (((kk2 << 2) + lq) ^ (lr & 7)) * 8);
          accv[nt] = __builtin_amdgcn_mfma_f32_16x16x32_f16(ap, bv, accv[nt], 0, 0, 0);
        }
      }
    }
    __syncthreads();  // next tile resident; all waves done with cur
    cur ^= 1;
  }

  // prefetch pass-2 tile 0 (overlaps the reduce); Kb[0] safe after barrier
  STAGE_K(Kb[0], 0);

  // row-sum: reduce across the lq dimension (lanes lr, lr+16, lr+32, lr+48)
  lsum1 += __shfl_xor(lsum1, 16);
  lsum1 += __shfl_xor(lsum1, 32);
  const float rl_row = 1.f / lsum1;  // 1/l for q-row `qrow`, uniform over lq

  // ---- ctx epilogue (decoder rows only) — scale unnormalized accumulator ----
  if (dec) {
    float rlj[4];
#pragma unroll
    for (int jj = 0; jj < 4; ++jj) rlj[jj] = __shfl(rl_row, lq * 4 + jj);
#pragma unroll
    for (int nt = 0; nt < 8; ++nt)
#pragma unroll
      for (int jj = 0; jj < 4; ++jj) {
        int sd = q0 + w * 16 + lq * 4 + jj - Ee;
        ctx[((size_t)b * Dd + sd) * Hh + h * HDd + nt * 16 + lr] = f2h(accv[nt][jj] * rlj[jj]);
      }
  }

  __syncthreads();  // pass-2 tile 0 resident (full drain incl. ctx stores — once)

  // ---- pass 2: normalized attn write (K dbuf, counted-vmcnt barrier/tile) ----
  cur = 0;
  for (int kt = 0; kt < kt_lim; ++kt) {
    if (kt + 1 < kt_lim) STAGE_K(Kb[cur ^ 1], kt + 1);
    __builtin_amdgcn_sched_barrier(0);  // pin staging loads BEFORE the nt stores
    const f16* Kp = Kb[cur];
#pragma unroll
    for (int j = 0; j < 4; ++j) {
      f32x4 sc = {0.f, 0.f, 0.f, 0.f};
#pragma unroll
      for (int kk = 0; kk < 4; ++kk) {
        half8 bk = *(const half8*)(Kp + (j * 16 + lr) * 128 + (((kk << 2) + lq) ^ (lr & 7)) * 8);
        sc = __builtin_amdgcn_mfma_f32_16x16x32_f16(bk, aq[kk], sc, 0, 0, 0);  // SWAPPED
      }
      const int c0 = kt * 64 + j * 16 + lq * 4;
      f32x4 pv4;
#pragma unroll
      for (int jj = 0; jj < 4; ++jj) {
        const int col = c0 + jj;
        bool masked = dec && col >= Ee && col > qrow;
        pv4[jj] = masked ? 0.f : __expf(sc[jj] * SCALE) * rl_row;
      }
      __builtin_nontemporal_store(pv4, (f32x4*)(attn + (bh * Ss + qrow) * (size_t)Ss + c0));
    }
    // Counted-vmcnt barrier (T4): wait for the 4 staging loads (oldest), leave
    // this tile's 4 nt stores in flight across the next tile's compute.
    asm volatile("s_waitcnt vmcnt(4) lgkmcnt(0)" ::: "memory");
    __builtin_amdgcn_sched_barrier(0);
    __builtin_amdgcn_s_barrier();
    __builtin_amdgcn_sched_barrier(0);
    cur ^= 1;
  }

  // ---- zero-fill fully-masked attn columns (nt, inside kernel — r10-proven) ----
  {
    const int zc0 = kt_lim * 64;
    const int Z = Ss - zc0;
    if (Z > 0) {
      const int per_row = Z >> 2;
      for (int idx = tid; idx < 64 * per_row; idx += 256) {
        int r = idx / per_row;
        int cc = (idx - r * per_row) << 2;
        f32x4 z = {0.f, 0.f, 0.f, 0.f};
        __builtin_nontemporal_store(z, (f32x4*)(attn + (bh * Ss + q0 + r) * (size_t)Ss + zc0 + cc));
      }
    }
  }
#undef STAGE_K
#undef STAGE_V
}

// ---------------- launch ----------------
extern "C" void kernel_launch(void* const* d_in, const int* in_sizes, int n_in,
                              void* d_out, int out_size, void* d_ws, size_t ws_size,
                              hipStream_t stream) {
  const float* hidden  = (const float*)d_in[0];
  const float* encoder = (const float*)d_in[1];
  const float* cosp    = (const float*)d_in[2];
  const float* sinp    = (const float*)d_in[3];
  // d_in[4] attention_mask: deterministic causal tril, reproduced arithmetically
  const float* Wq = (const float*)d_in[5];
  const float* Wk = (const float*)d_in[6];
  const float* Wv = (const float*)d_in[7];
  const float* Wo = (const float*)d_in[8];

  f16* ws = (f16*)d_ws;
  size_t off = 0;
  f16* hs_f = ws + off; off += (size_t)Bb * Ss * Hh;         // 8,388,608
  f16* W_f  = ws + off; off += (size_t)4 * Hh * Hh;          // 16,777,216
  f16* q_f  = ws + off; off += (size_t)Bb * NHh * Ss * HDd;  // 8,388,608
  f16* k_f  = ws + off; off += (size_t)Bb * NHh * Ss * HDd;
  f16* v_f  = ws + off; off += (size_t)Bb * NHh * Ss * HDd;
  f16* ctx_f = ws + off; off += (size_t)Bb * Dd * Hh;        // total ~104 MB

  float* outp = (float*)d_out;
  float* attnp = outp + (size_t)Bb * Dd * Hh;

  convert_hs_k<<<4096, 256, 0, stream>>>(hidden, encoder, hs_f);
  convert_w_k<<<dim3(2048, 4), 256, 0, stream>>>(Wq, Wk, Wv, Wo, W_f);
  gemm_k<0><<<dim3(16, 32), 256, 0, stream>>>(hs_f, W_f + 0 * (size_t)Hh * Hh, q_f);
  gemm_k<0><<<dim3(16, 32), 256, 0, stream>>>(hs_f, W_f + 1 * (size_t)Hh * Hh, k_f);
  gemm_k<1><<<dim3(16, 32), 256, 0, stream>>>(hs_f, W_f + 2 * (size_t)Hh * Hh, v_f);
  rope_k<<<8192, 256, 0, stream>>>(q_f, k_f, cosp, sinp);
  attn_k<<<1024, 256, 0, stream>>>(q_f, k_f, v_f, attnp, ctx_f);
  gemm_k<2><<<dim3(16, 16), 256, 0, stream>>>(ctx_f, W_f + 3 * (size_t)Hh * Hh, outp);
}

// Round 15
// 425.023 us; speedup vs baseline: 1.0115x; 1.0115x over previous
//
#include <hip/hip_runtime.h>
#include <cstdint>
#include <cstddef>

typedef _Float16 f16;
typedef __attribute__((ext_vector_type(8))) _Float16 half8;
typedef __attribute__((ext_vector_type(4))) float f32x4;

constexpr int Bb = 2, Ee = 1024, Dd = 1024, Hh = 2048, NHh = 16, HDd = 128, Ss = 2048;
constexpr float SCALE = 0.08838834764831845f;  // HD^-0.5
constexpr int PSTR = 84;                       // Plds row stride (f16) — bank-spread

#define DEVINL __device__ __forceinline__
#define GLD_LDS(gp, lp) \
  __builtin_amdgcn_global_load_lds((const __attribute__((address_space(1))) void*)(gp), \
                                   (__attribute__((address_space(3))) void*)(lp), 16, 0, 0)

DEVINL f16 f2h(float x) { return (f16)x; }
DEVINL float h2f(f16 x) { return (float)x; }

// ---------------- conversions ----------------
__global__ void convert_hs_k(const float* __restrict__ hid, const float* __restrict__ enc,
                             f16* __restrict__ dst) {
  size_t idx = ((size_t)blockIdx.x * 256 + threadIdx.x) * 8;  // over B*S*H = 2^23
  int b = (int)(idx >> 22);
  size_t r = idx & ((1ull << 22) - 1);
  int s = (int)(r >> 11);
  int hc = (int)(r & 2047);
  const float* src = (s < Ee) ? (enc + (((size_t)b * Ee + s) << 11) + hc)
                              : (hid + (((size_t)b * Dd + (s - Ee)) << 11) + hc);
  float4 x0 = *(const float4*)src;
  float4 x1 = *(const float4*)(src + 4);
  union { f16 u[8]; uint4 v; } o;
  o.u[0] = f2h(x0.x); o.u[1] = f2h(x0.y); o.u[2] = f2h(x0.z); o.u[3] = f2h(x0.w);
  o.u[4] = f2h(x1.x); o.u[5] = f2h(x1.y); o.u[6] = f2h(x1.z); o.u[7] = f2h(x1.w);
  *(uint4*)(dst + idx) = o.v;
}

__global__ void convert_w_k(const float* __restrict__ w0, const float* __restrict__ w1,
                            const float* __restrict__ w2, const float* __restrict__ w3,
                            f16* __restrict__ dst) {
  const float* srcs[4] = {w0, w1, w2, w3};
  int z = blockIdx.y;
  size_t idx = ((size_t)blockIdx.x * 256 + threadIdx.x) * 8;  // over H*H = 2^22
  const float* s = srcs[z] + idx;
  f16* d = dst + (size_t)z * Hh * Hh + idx;
  float4 x0 = *(const float4*)s;
  float4 x1 = *(const float4*)(s + 4);
  union { f16 u[8]; uint4 v; } o;
  o.u[0] = f2h(x0.x); o.u[1] = f2h(x0.y); o.u[2] = f2h(x0.z); o.u[3] = f2h(x0.w);
  o.u[4] = f2h(x1.x); o.u[5] = f2h(x1.y); o.u[6] = f2h(x1.z); o.u[7] = f2h(x1.w);
  *(uint4*)d = o.v;
}

// ---------------- GEMM: C[M x 2048] = A[M x 2048] * Bw[2048 x 2048]^T ----------------
// (r5/r10-exact, known-good)  MODE 0: per-head f16 [b][h][s][hd] (q,k)
// MODE 1: per-head f16 transposed [b][h][hd][s] (v)   MODE 2: f32 row-major (out)
template <int MODE>
__global__ __launch_bounds__(256) void gemm_k(const f16* __restrict__ A,
                                              const f16* __restrict__ Bw,
                                              void* __restrict__ Cout) {
  __shared__ f16 Alds[128 * 64];
  __shared__ f16 Blds[128 * 64];
  const int tid = threadIdx.x;
  const int lane = tid & 63, w = tid >> 6;
  const int lr = lane & 15, lq = lane >> 4;
  const int m0 = blockIdx.y * 128, n0 = blockIdx.x * 128;
  const int wm = (w >> 1) * 64, wn = (w & 1) * 64;
  f32x4 acc[4][4] = {};

  for (int k0 = 0; k0 < 2048; k0 += 64) {
    __syncthreads();
#pragma unroll
    for (int t = 0; t < 4; ++t) {
      int c = t * 256 + tid;
      int row = c >> 3, cof = (c & 7) << 3;
      const f16* ga = A + ((size_t)(m0 + row) << 11) + k0 + cof;
      const f16* gb = Bw + ((size_t)(n0 + row) << 11) + k0 + cof;
      int lo = (t * 256 + w * 64) * 8;
      GLD_LDS(ga, Alds + lo);
      GLD_LDS(gb, Blds + lo);
    }
    __syncthreads();
#pragma unroll
    for (int kk = 0; kk < 2; ++kk) {
      half8 af[4], bf[4];
#pragma unroll
      for (int i = 0; i < 4; ++i) {
        af[i] = *(const half8*)(Alds + (wm + i * 16 + lr) * 64 + kk * 32 + lq * 8);
        bf[i] = *(const half8*)(Blds + (wn + i * 16 + lr) * 64 + kk * 32 + lq * 8);
      }
#pragma unroll
      for (int i = 0; i < 4; ++i)
#pragma unroll
        for (int j = 0; j < 4; ++j)
          acc[i][j] = __builtin_amdgcn_mfma_f32_16x16x32_f16(af[i], bf[j], acc[i][j], 0, 0, 0);
    }
  }

#pragma unroll
  for (int i = 0; i < 4; ++i) {
#pragma unroll
    for (int j = 0; j < 4; ++j) {
      const int col = n0 + wn + j * 16 + lr;
#pragma unroll
      for (int jj = 0; jj < 4; ++jj) {
        const int row = m0 + wm + i * 16 + lq * 4 + jj;
        float v = acc[i][j][jj];
        if constexpr (MODE == 2) {
          ((float*)Cout)[((size_t)row << 11) + col] = v;
        } else {
          const int bb = row >> 11, s = row & 2047;
          const int hh = col >> 7, hd = col & 127;
          size_t o;
          if constexpr (MODE == 0)
            o = ((((size_t)bb * NHh + hh) * Ss + s) << 7) + hd;
          else
            o = ((((size_t)bb * NHh + hh) * HDd + hd) << 11) + s;
          ((f16*)Cout)[o] = f2h(v);
        }
      }
    }
  }
}

// ---------------- RoPE on decoder rows of q,k ----------------
__global__ void rope_k(f16* __restrict__ q, f16* __restrict__ k,
                       const float* __restrict__ cosp, const float* __restrict__ sinp) {
  size_t idx = (size_t)blockIdx.x * 256 + threadIdx.x;  // B*NH*D*64 = 2^21
  const int d = (int)(idx & 63);
  const int sdec = (int)((idx >> 6) & 1023);
  const int h = (int)((idx >> 16) & 15);
  const int b = (int)(idx >> 20);
  const size_t base = (((size_t)b * NHh + h) * Ss + Ee + sdec) * HDd;
  const size_t cbase = ((size_t)b * Dd + sdec) * HDd;
  const float c1 = cosp[cbase + d], s1 = sinp[cbase + d];
  const float c2 = cosp[cbase + d + 64], s2 = sinp[cbase + d + 64];
  {
    float x1 = h2f(q[base + d]), x2 = h2f(q[base + d + 64]);
    q[base + d] = f2h(x1 * c1 - x2 * s1);
    q[base + d + 64] = f2h(x2 * c2 + x1 * s2);
  }
  {
    float x1 = h2f(k[base + d]), x2 = h2f(k[base + d + 64]);
    k[base + d] = f2h(x1 * c1 - x2 * s1);
    k[base + d + 64] = f2h(x2 * c2 + x1 * s2);
  }
}

// ---------------- fused attention (r10-exact, measured 425.8 us total) ----------------
// Swapped QK^T (mfma(K,Q)): lane holds 4 consecutive key-cols of one q-row ->
// f32x4 nt stores in pass 2, scalar lsum in pass 1 (2 shfl reduce).
// Pass 1: K+V dbuf, QK^T -> Plds(unnormalized exp) -> PV, one barrier/tile.
// Pass 2: K dbuf, recompute p = exp(s)*rl, f32x4 nt store, one barrier/tile.
// nt stores throughout (r11: plain +48us; r12: stream-head fill +25us;
// r14: counted-vmcnt barrier neutral -> plain __syncthreads kept).
__global__ __launch_bounds__(256) void attn_k(const f16* __restrict__ qw,
                                              const f16* __restrict__ kw,
                                              const f16* __restrict__ vw,
                                              float* __restrict__ attn,
                                              f16* __restrict__ ctx) {
  __shared__ f16 Kb[2][8192];
  __shared__ f16 Vb[2][8192];
  __shared__ f16 Plds[4][16 * PSTR];
  const int tid = threadIdx.x;
  const int lane = tid & 63, w = tid >> 6;
  const int lr = lane & 15, lq = lane >> 4;

  // XCD-aware remap: 8 chunks of 128 blocks; heavy-first q-tile order.
  const int n = blockIdx.x;
  const int orig = (n & 7) * 128 + (n >> 3);
  const int qt = orig & 31;
  const int h = (orig >> 5) & 15;
  const int b = orig >> 9;
  const int q0 = (31 - qt) * 64;
  const bool dec = q0 >= Ee;
  const int kt_lim = dec ? (q0 / 64 + 1) : (Ee / 64);
  const size_t bh = (size_t)b * NHh + h;

#define STAGE_K(dst, kt_)                                                        \
  {                                                                              \
    _Pragma("unroll") for (int t = 0; t < 4; ++t) {                              \
      int c = t * 256 + tid;                                                     \
      int row = c >> 4;                                                          \
      int gs = (c & 15) ^ (row & 7);                                             \
      GLD_LDS(kw + (bh * Ss + (kt_) * 64 + row) * HDd + gs * 8, (dst) + c * 8);  \
    }                                                                            \
  }
#define STAGE_V(dst, kt_)                                                        \
  {                                                                              \
    _Pragma("unroll") for (int t = 0; t < 4; ++t) {                              \
      int c = t * 256 + tid;                                                     \
      int row = c >> 3;                                                          \
      int gs = (c & 7) ^ (row & 7);                                              \
      GLD_LDS(vw + (bh * HDd + row) * Ss + (kt_) * 64 + gs * 8, (dst) + c * 8);  \
    }                                                                            \
  }

  // Q fragments: wave's 16 rows x 128 dims, kept in registers
  const f16* qbase = qw + (bh * Ss + q0 + w * 16 + lr) * HDd + lq * 8;
  half8 aq[4];
#pragma unroll
  for (int kk = 0; kk < 4; ++kk) aq[kk] = *(const half8*)(qbase + kk * 32);

  const int qrow = q0 + w * 16 + lr;  // this lane's q-row (swapped layout)
  float lsum1 = 0.f;
  f32x4 accv[8] = {};

  // ---- pass 1: row sums + UNNORMALIZED PV (one barrier per tile) ----
  STAGE_K(Kb[0], 0);
  if (dec) STAGE_V(Vb[0], 0);
  __syncthreads();
  int cur = 0;
  for (int kt = 0; kt < kt_lim; ++kt) {
    if (kt + 1 < kt_lim) {
      STAGE_K(Kb[cur ^ 1], kt + 1);            // overlaps compute below
      if (dec) STAGE_V(Vb[cur ^ 1], kt + 1);
    }
    const f16* Kp = Kb[cur];
#pragma unroll
    for (int j = 0; j < 4; ++j) {
      f32x4 sc = {0.f, 0.f, 0.f, 0.f};
#pragma unroll
      for (int kk = 0; kk < 4; ++kk) {
        half8 bk = *(const half8*)(Kp + (j * 16 + lr) * 128 + (((kk << 2) + lq) ^ (lr & 7)) * 8);
        sc = __builtin_amdgcn_mfma_f32_16x16x32_f16(bk, aq[kk], sc, 0, 0, 0);  // SWAPPED
      }
      const int c0 = kt * 64 + j * 16 + lq * 4;
      union { f16 u[4]; uint2 v2; } pw;
#pragma unroll
      for (int jj = 0; jj < 4; ++jj) {
        const int col = c0 + jj;
        bool masked = dec && col >= Ee && col > qrow;
        float pu = masked ? 0.f : __expf(sc[jj] * SCALE);  // unnormalized, <= e^~6
        lsum1 += pu;
        pw.u[jj] = f2h(pu);
      }
      if (dec) *(uint2*)(&Plds[w][lr * PSTR + j * 16 + lq * 4]) = pw.v2;
    }
    if (dec) {
      // Plds[w] wave-private: same-wave lgkmcnt ordering suffices, no barrier.
#pragma unroll
      for (int kk2 = 0; kk2 < 2; ++kk2) {
        half8 ap = *(const half8*)(&Plds[w][lr * PSTR + kk2 * 32 + lq * 8]);
#pragma unroll
        for (int nt = 0; nt < 8; ++nt) {
          half8 bv = *(const half8*)(Vb[cur] + (nt * 16 + lr) * 64 + (((kk2 << 2) + lq) ^ (lr & 7)) * 8);
          accv[nt] = __builtin_amdgcn_mfma_f32_16x16x32_f16(ap, bv, accv[nt], 0, 0, 0);
        }
      }
    }
    __syncthreads();  // next tile resident; all waves done with cur
    cur ^= 1;
  }

  // prefetch pass-2 tile 0 (overlaps the reduce); Kb[0] safe after barrier
  STAGE_K(Kb[0], 0);

  // row-sum: reduce across the lq dimension (lanes lr, lr+16, lr+32, lr+48)
  lsum1 += __shfl_xor(lsum1, 16);
  lsum1 += __shfl_xor(lsum1, 32);
  const float rl_row = 1.f / lsum1;  // 1/l for q-row `qrow`, uniform over lq

  // ---- ctx epilogue (decoder rows only) — scale unnormalized accumulator ----
  // PV output rows are lq*4+jj (D-row = A-fragment index); fetch their rl.
  if (dec) {
    float rlj[4];
#pragma unroll
    for (int jj = 0; jj < 4; ++jj) rlj[jj] = __shfl(rl_row, lq * 4 + jj);
#pragma unroll
    for (int nt = 0; nt < 8; ++nt)
#pragma unroll
      for (int jj = 0; jj < 4; ++jj) {
        int sd = q0 + w * 16 + lq * 4 + jj - Ee;
        ctx[((size_t)b * Dd + sd) * Hh + h * HDd + nt * 16 + lr] = f2h(accv[nt][jj] * rlj[jj]);
      }
  }

  __syncthreads();  // pass-2 tile 0 resident

  // ---- pass 2: normalized attn write only (K dbuf, one barrier per tile) ----
  // Swapped layout: lane holds 4 consecutive cols of row `qrow` -> f32x4 store.
  cur = 0;
  for (int kt = 0; kt < kt_lim; ++kt) {
    if (kt + 1 < kt_lim) STAGE_K(Kb[cur ^ 1], kt + 1);
    const f16* Kp = Kb[cur];
#pragma unroll
    for (int j = 0; j < 4; ++j) {
      f32x4 sc = {0.f, 0.f, 0.f, 0.f};
#pragma unroll
      for (int kk = 0; kk < 4; ++kk) {
        half8 bk = *(const half8*)(Kp + (j * 16 + lr) * 128 + (((kk << 2) + lq) ^ (lr & 7)) * 8);
        sc = __builtin_amdgcn_mfma_f32_16x16x32_f16(bk, aq[kk], sc, 0, 0, 0);  // SWAPPED
      }
      const int c0 = kt * 64 + j * 16 + lq * 4;
      f32x4 pv4;
#pragma unroll
      for (int jj = 0; jj < 4; ++jj) {
        const int col = c0 + jj;
        bool masked = dec && col >= Ee && col > qrow;
        pv4[jj] = masked ? 0.f : __expf(sc[jj] * SCALE) * rl_row;
      }
      __builtin_nontemporal_store(pv4, (f32x4*)(attn + (bh * Ss + qrow) * (size_t)Ss + c0));
    }
    __syncthreads();
    cur ^= 1;
  }

  // ---- zero-fill fully-masked attn columns (nt, inside kernel) ----
  {
    const int zc0 = kt_lim * 64;
    const int Z = Ss - zc0;
    if (Z > 0) {
      const int per_row = Z >> 2;
      for (int idx = tid; idx < 64 * per_row; idx += 256) {
        int r = idx / per_row;
        int cc = (idx - r * per_row) << 2;
        f32x4 z = {0.f, 0.f, 0.f, 0.f};
        __builtin_nontemporal_store(z, (f32x4*)(attn + (bh * Ss + q0 + r) * (size_t)Ss + zc0 + cc));
      }
    }
  }
#undef STAGE_K
#undef STAGE_V
}

// ---------------- launch ----------------
extern "C" void kernel_launch(void* const* d_in, const int* in_sizes, int n_in,
                              void* d_out, int out_size, void* d_ws, size_t ws_size,
                              hipStream_t stream) {
  const float* hidden  = (const float*)d_in[0];
  const float* encoder = (const float*)d_in[1];
  const float* cosp    = (const float*)d_in[2];
  const float* sinp    = (const float*)d_in[3];
  // d_in[4] attention_mask: deterministic causal tril, reproduced arithmetically
  const float* Wq = (const float*)d_in[5];
  const float* Wk = (const float*)d_in[6];
  const float* Wv = (const float*)d_in[7];
  const float* Wo = (const float*)d_in[8];

  f16* ws = (f16*)d_ws;
  size_t off = 0;
  f16* hs_f = ws + off; off += (size_t)Bb * Ss * Hh;         // 8,388,608
  f16* W_f  = ws + off; off += (size_t)4 * Hh * Hh;          // 16,777,216
  f16* q_f  = ws + off; off += (size_t)Bb * NHh * Ss * HDd;  // 8,388,608
  f16* k_f  = ws + off; off += (size_t)Bb * NHh * Ss * HDd;
  f16* v_f  = ws + off; off += (size_t)Bb * NHh * Ss * HDd;
  f16* ctx_f = ws + off; off += (size_t)Bb * Dd * Hh;        // total ~104 MB

  float* outp = (float*)d_out;
  float* attnp = outp + (size_t)Bb * Dd * Hh;

  convert_hs_k<<<4096, 256, 0, stream>>>(hidden, encoder, hs_f);
  convert_w_k<<<dim3(2048, 4), 256, 0, stream>>>(Wq, Wk, Wv, Wo, W_f);
  gemm_k<0><<<dim3(16, 32), 256, 0, stream>>>(hs_f, W_f + 0 * (size_t)Hh * Hh, q_f);
  gemm_k<0><<<dim3(16, 32), 256, 0, stream>>>(hs_f, W_f + 1 * (size_t)Hh * Hh, k_f);
  gemm_k<1><<<dim3(16, 32), 256, 0, stream>>>(hs_f, W_f + 2 * (size_t)Hh * Hh, v_f);
  rope_k<<<8192, 256, 0, stream>>>(q_f, k_f, cosp, sinp);
  attn_k<<<1024, 256, 0, stream>>>(q_f, k_f, v_f, attnp, ctx_f);
  gemm_k<2><<<dim3(16, 16), 256, 0, stream>>>(ctx_f, W_f + 3 * (size_t)Hh * Hh, outp);
}